// Round 9
// baseline (1366.009 us; speedup 1.0000x reference)
//
#include <hip/hip_runtime.h>
#include <math.h>

#define NB    4
#define PP    1024
#define DD    32
#define MAXIT 30
#define NBLKS 256
#define BTHR  256
#define AGENT __HIP_MEMORY_SCOPE_AGENT

// Persistent-kernel state. Barrier counters are MONOTONIC across calls/replays
// (epoch base re-read each call); all other state is rewritten each call.
__device__ unsigned g_cnt[16 * 16];   // 16 group counters, 64 B apart
__device__ unsigned g_root;
__device__ unsigned g_epoch;
__device__ float    g_u[NB * PP], g_v[NB * PP];
__device__ double   g_errpart[NBLKS];
__device__ double   g_costpart[NBLKS];

// Two-level global barrier (verified in round 6): 256 blocks -> 16 groups x 16.
__device__ __forceinline__ void gbar(unsigned target, int tid, int blk)
{
    __syncthreads();
    if (tid == 0) {
        const unsigned old = __hip_atomic_fetch_add(&g_cnt[(blk & 15) << 4], 1u,
                                                    __ATOMIC_ACQ_REL, AGENT);
        if (old == target * 16u + 15u) {                 // last in group
            const unsigned o2 = __hip_atomic_fetch_add(&g_root, 1u,
                                                       __ATOMIC_ACQ_REL, AGENT);
            if (o2 == target * 16u + 15u)                // last group
                __hip_atomic_store(&g_epoch, target + 1u, __ATOMIC_RELEASE, AGENT);
        }
        while (__hip_atomic_load(&g_epoch, __ATOMIC_ACQUIRE, AGENT) <= target)
            __builtin_amdgcn_s_sleep(2);
    }
    __syncthreads();
}

// ---------------------------------------------------------------------------
// One persistent kernel, 256 blocks x 256 thr, 1 block/CU (LDS-limited).
// Block b: batch n = b>>6, rows/cols [p0, p0+16), p0 = (b&63)*16.
// C rows and C^T rows live in LDS (64 KB each); wave w owns 4 rows.
// Lane l covers global cols/rows q = l + 64c, c = 0..15.
// ---------------------------------------------------------------------------
__global__ __launch_bounds__(BTHR, 1)
void sinkhorn_kernel(const float* __restrict__ x, const float* __restrict__ y,
                     const float* __restrict__ xw, const float* __restrict__ yw,
                     float* __restrict__ out)
{
    const int tid = threadIdx.x, lane = tid & 63, wid = tid >> 6;
    const int blk = blockIdx.x;
    const int n = blk >> 6, nbase = n << 10;
    const int p0 = (blk & 63) << 4;

    const unsigned base = __hip_atomic_load(&g_epoch, __ATOMIC_RELAXED, AGENT);
    unsigned ls = 0;

    __shared__ float  C_lds [16][PP];    // 64 KB  C[p0+r][q]
    __shared__ float  Ct_lds[16][PP];    // 64 KB  C[p][p0+r] (transposed rows)
    __shared__ float  vec_lds[PP];       // 4 KB   staged v (u-phase) / u (v-phase)
    __shared__ float  rows_s[16][DD];    // 2 KB   own x- or y-rows for build
    __shared__ double red_a[4], red_b[4];

    // ---- global weight sums (deterministic, identical in every block) ----
    {
        double sx = 0.0, sy = 0.0;
        for (int i = tid; i < NB * PP; i += BTHR) { sx += (double)xw[i]; sy += (double)yw[i]; }
#pragma unroll
        for (int o = 32; o; o >>= 1) { sx += __shfl_xor(sx, o); sy += __shfl_xor(sy, o); }
        if (lane == 0) { red_a[wid] = sx; red_b[wid] = sy; }
    }
    __syncthreads();
    const double Sx = ((red_a[0] + red_a[1]) + red_a[2]) + red_a[3];
    const double Sy = ((red_b[0] + red_b[1]) + red_b[2]) + red_b[3];
    __syncthreads();

    // ---- own-row log-weights ----
    float lmu[4], lnu[4];
#pragma unroll
    for (int rr = 0; rr < 4; ++rr) {
        const int gr = nbase + p0 + (wid << 2) + rr;
        lmu[rr] = (float)log((double)xw[gr] / Sx + 1e-8);
        lnu[rr] = (float)log((double)yw[gr] / Sy + 1e-8);
    }

    // ---- build C rows into LDS (x own rows vs all y) ----
    for (int i = tid; i < 16 * DD; i += BTHR)
        rows_s[i >> 5][i & 31] = x[((size_t)(nbase + p0 + (i >> 5)) << 5) + (i & 31)];
    __syncthreads();
    {
        const float4* op0 = reinterpret_cast<const float4*>(y + ((size_t)(nbase + tid      ) << 5));
        const float4* op1 = reinterpret_cast<const float4*>(y + ((size_t)(nbase + tid + 256) << 5));
        const float4* op2 = reinterpret_cast<const float4*>(y + ((size_t)(nbase + tid + 512) << 5));
        const float4* op3 = reinterpret_cast<const float4*>(y + ((size_t)(nbase + tid + 768) << 5));
        float acc0[16], acc1[16], acc2[16], acc3[16];
#pragma unroll
        for (int r = 0; r < 16; ++r) { acc0[r]=0.f; acc1[r]=0.f; acc2[r]=0.f; acc3[r]=0.f; }
#pragma unroll
        for (int j = 0; j < 8; ++j) {
            const float4 f0 = op0[j], f1 = op1[j], f2 = op2[j], f3 = op3[j];
#pragma unroll
            for (int r = 0; r < 16; ++r) {
                const float4 rv = *reinterpret_cast<const float4*>(&rows_s[r][4*j]);
                float d;
                d = rv.x-f0.x; acc0[r]=fmaf(d,d,acc0[r]);
                d = rv.y-f0.y; acc0[r]=fmaf(d,d,acc0[r]);
                d = rv.z-f0.z; acc0[r]=fmaf(d,d,acc0[r]);
                d = rv.w-f0.w; acc0[r]=fmaf(d,d,acc0[r]);
                d = rv.x-f1.x; acc1[r]=fmaf(d,d,acc1[r]);
                d = rv.y-f1.y; acc1[r]=fmaf(d,d,acc1[r]);
                d = rv.z-f1.z; acc1[r]=fmaf(d,d,acc1[r]);
                d = rv.w-f1.w; acc1[r]=fmaf(d,d,acc1[r]);
                d = rv.x-f2.x; acc2[r]=fmaf(d,d,acc2[r]);
                d = rv.y-f2.y; acc2[r]=fmaf(d,d,acc2[r]);
                d = rv.z-f2.z; acc2[r]=fmaf(d,d,acc2[r]);
                d = rv.w-f2.w; acc2[r]=fmaf(d,d,acc2[r]);
                d = rv.x-f3.x; acc3[r]=fmaf(d,d,acc3[r]);
                d = rv.y-f3.y; acc3[r]=fmaf(d,d,acc3[r]);
                d = rv.z-f3.z; acc3[r]=fmaf(d,d,acc3[r]);
                d = rv.w-f3.w; acc3[r]=fmaf(d,d,acc3[r]);
            }
        }
#pragma unroll
        for (int r = 0; r < 16; ++r) {
            C_lds[r][tid      ] = acc0[r];
            C_lds[r][tid + 256] = acc1[r];
            C_lds[r][tid + 512] = acc2[r];
            C_lds[r][tid + 768] = acc3[r];
        }
    }
    __syncthreads();

    // ---- build C^T rows into LDS (y own rows vs all x) ----
    for (int i = tid; i < 16 * DD; i += BTHR)
        rows_s[i >> 5][i & 31] = y[((size_t)(nbase + p0 + (i >> 5)) << 5) + (i & 31)];
    __syncthreads();
    {
        const float4* op0 = reinterpret_cast<const float4*>(x + ((size_t)(nbase + tid      ) << 5));
        const float4* op1 = reinterpret_cast<const float4*>(x + ((size_t)(nbase + tid + 256) << 5));
        const float4* op2 = reinterpret_cast<const float4*>(x + ((size_t)(nbase + tid + 512) << 5));
        const float4* op3 = reinterpret_cast<const float4*>(x + ((size_t)(nbase + tid + 768) << 5));
        float acc0[16], acc1[16], acc2[16], acc3[16];
#pragma unroll
        for (int r = 0; r < 16; ++r) { acc0[r]=0.f; acc1[r]=0.f; acc2[r]=0.f; acc3[r]=0.f; }
#pragma unroll
        for (int j = 0; j < 8; ++j) {
            const float4 f0 = op0[j], f1 = op1[j], f2 = op2[j], f3 = op3[j];
#pragma unroll
            for (int r = 0; r < 16; ++r) {
                const float4 rv = *reinterpret_cast<const float4*>(&rows_s[r][4*j]);
                float d;
                d = rv.x-f0.x; acc0[r]=fmaf(d,d,acc0[r]);
                d = rv.y-f0.y; acc0[r]=fmaf(d,d,acc0[r]);
                d = rv.z-f0.z; acc0[r]=fmaf(d,d,acc0[r]);
                d = rv.w-f0.w; acc0[r]=fmaf(d,d,acc0[r]);
                d = rv.x-f1.x; acc1[r]=fmaf(d,d,acc1[r]);
                d = rv.y-f1.y; acc1[r]=fmaf(d,d,acc1[r]);
                d = rv.z-f1.z; acc1[r]=fmaf(d,d,acc1[r]);
                d = rv.w-f1.w; acc1[r]=fmaf(d,d,acc1[r]);
                d = rv.x-f2.x; acc2[r]=fmaf(d,d,acc2[r]);
                d = rv.y-f2.y; acc2[r]=fmaf(d,d,acc2[r]);
                d = rv.z-f2.z; acc2[r]=fmaf(d,d,acc2[r]);
                d = rv.w-f2.w; acc2[r]=fmaf(d,d,acc2[r]);
                d = rv.x-f3.x; acc3[r]=fmaf(d,d,acc3[r]);
                d = rv.y-f3.y; acc3[r]=fmaf(d,d,acc3[r]);
                d = rv.z-f3.z; acc3[r]=fmaf(d,d,acc3[r]);
                d = rv.w-f3.w; acc3[r]=fmaf(d,d,acc3[r]);
            }
        }
#pragma unroll
        for (int r = 0; r < 16; ++r) {
            Ct_lds[r][tid      ] = acc0[r];
            Ct_lds[r][tid + 256] = acc1[r];
            Ct_lds[r][tid + 512] = acc2[r];
            Ct_lds[r][tid + 768] = acc3[r];
        }
    }
    // (visibility of C/Ct covered by the staging __syncthreads below)

    // ---- Sinkhorn loop ----
    float ureg[4] = {0.f, 0.f, 0.f, 0.f};

    for (int it = 0; it < MAXIT; ++it) {
        // -- stage v (iter 0: zeros; later: written this call) --
        if (it == 0) {
            for (int i = tid; i < PP; i += BTHR) vec_lds[i] = 0.f;
        } else {
            for (int i = tid; i < PP; i += BTHR)
                vec_lds[i] = __hip_atomic_load(&g_v[nbase + i], __ATOMIC_RELAXED, AGENT);
        }
        __syncthreads();

        float vv10[16];
#pragma unroll
        for (int c = 0; c < 16; ++c) vv10[c] = vec_lds[lane + (c << 6)] * 10.f;

        // -- u update: u_new[p] = 0.1*(logmu[p] - lse_q((v[q]-C[p,q])*10)) --
        double du = 0.0;
        float myu = 0.f;
#pragma unroll
        for (int rr = 0; rr < 4; ++rr) {
            const int lr = (wid << 2) + rr;
            float tv[16], mx = -1e30f;
#pragma unroll
            for (int c = 0; c < 16; ++c) {
                tv[c] = fmaf(C_lds[lr][lane + (c << 6)], -10.f, vv10[c]);
                mx = fmaxf(mx, tv[c]);
            }
#pragma unroll
            for (int o = 32; o; o >>= 1) mx = fmaxf(mx, __shfl_xor(mx, o));
            float s = 0.f;
#pragma unroll
            for (int c = 0; c < 16; ++c) s += __expf(tv[c] - mx);
#pragma unroll
            for (int o = 32; o; o >>= 1) s += __shfl_xor(s, o);
            const float un = 0.1f * (lmu[rr] - (mx + __logf(s)));
            du += fabs((double)un - (double)ureg[rr]);
            ureg[rr] = un;                     // loop breaks before any frozen iter
            if (lane == rr) myu = un;          // rr compile-time -> no dyn reg index
        }
        if (lane < 4)
            __hip_atomic_store(&g_u[nbase + p0 + (wid << 2) + lane], myu,
                               __ATOMIC_RELAXED, AGENT);
        if (lane == 0) red_a[wid] = du;
        __syncthreads();
        if (tid == 0)
            __hip_atomic_store(&g_errpart[blk],
                               ((red_a[0] + red_a[1]) + red_a[2]) + red_a[3],
                               __ATOMIC_RELAXED, AGENT);

        gbar(base + ls, tid, blk); ++ls;       // u + err partials visible

        // -- stage u; every block redundantly reduces err (deterministic) --
        for (int i = tid; i < PP; i += BTHR)
            vec_lds[i] = __hip_atomic_load(&g_u[nbase + i], __ATOMIC_RELAXED, AGENT);
        double ep = __hip_atomic_load(&g_errpart[tid], __ATOMIC_RELAXED, AGENT);
#pragma unroll
        for (int o = 32; o; o >>= 1) ep += __shfl_xor(ep, o);
        if (lane == 0) red_b[wid] = ep;
        __syncthreads();                       // covers vec_lds staging too
        const int done_next =
            (((red_b[0] + red_b[1]) + red_b[2]) + red_b[3]) < 0.4;  // total<0.4 <=> mean<0.1

        float uu10[16];
#pragma unroll
        for (int c = 0; c < 16; ++c) uu10[c] = vec_lds[lane + (c << 6)] * 10.f;

        // -- v update: v_new[q] = 0.1*(lognu[q] - lse_p((u[p]-C[p,q])*10)) --
        float myv = 0.f;
#pragma unroll
        for (int rr = 0; rr < 4; ++rr) {
            const int lr = (wid << 2) + rr;
            float tv[16], mx = -1e30f;
#pragma unroll
            for (int c = 0; c < 16; ++c) {
                tv[c] = fmaf(Ct_lds[lr][lane + (c << 6)], -10.f, uu10[c]);
                mx = fmaxf(mx, tv[c]);
            }
#pragma unroll
            for (int o = 32; o; o >>= 1) mx = fmaxf(mx, __shfl_xor(mx, o));
            float s = 0.f;
#pragma unroll
            for (int c = 0; c < 16; ++c) s += __expf(tv[c] - mx);
#pragma unroll
            for (int o = 32; o; o >>= 1) s += __shfl_xor(s, o);
            const float vn = 0.1f * (lnu[rr] - (mx + __logf(s)));
            if (lane == rr) myv = vn;
        }
        if (lane < 4)
            __hip_atomic_store(&g_v[nbase + p0 + (wid << 2) + lane], myv,
                               __ATOMIC_RELAXED, AGENT);

        gbar(base + ls, tid, blk); ++ls;       // v visible

        if (done_next) break;                  // uniform across all blocks
    }

    // ---- cost = sum_pq exp((u_p + v_q - C_pq)*10) * C_pq (f64 partials) ----
    for (int i = tid; i < PP; i += BTHR)
        vec_lds[i] = __hip_atomic_load(&g_v[nbase + i], __ATOMIC_RELAXED, AGENT);
    __syncthreads();

    double part = 0.0;
#pragma unroll
    for (int rr = 0; rr < 4; ++rr) {
        const int lr = (wid << 2) + rr;
        const float u10 = ureg[rr] * 10.f;
#pragma unroll
        for (int c = 0; c < 16; ++c) {
            const float cv = C_lds[lr][lane + (c << 6)];
            const float a  = fmaf(cv, -10.f, fmaf(vec_lds[lane + (c << 6)], 10.f, u10));
            part += (double)__expf(a) * (double)cv;
        }
    }
#pragma unroll
    for (int o = 32; o; o >>= 1) part += __shfl_xor(part, o);
    if (lane == 0) red_a[wid] = part;
    __syncthreads();
    if (tid == 0)
        __hip_atomic_store(&g_costpart[blk],
                           ((red_a[0] + red_a[1]) + red_a[2]) + red_a[3],
                           __ATOMIC_RELAXED, AGENT);

    gbar(base + ls, tid, blk); ++ls;           // cost partials visible

    if (blk < NB && tid < 64) {                // block n reduces its batch's 64 partials
        double s2 = __hip_atomic_load(&g_costpart[(blk << 6) + tid], __ATOMIC_RELAXED, AGENT);
#pragma unroll
        for (int o = 32; o; o >>= 1) s2 += __shfl_xor(s2, o);
        if (tid == 0) out[blk] = (float)s2;
    }
}

// ---------------------------------------------------------------------------
extern "C" void kernel_launch(void* const* d_in, const int* in_sizes, int n_in,
                              void* d_out, int out_size, void* d_ws, size_t ws_size,
                              hipStream_t stream)
{
    (void)in_sizes; (void)n_in; (void)out_size; (void)d_ws; (void)ws_size;
    const float* x  = (const float*)d_in[0];
    const float* y  = (const float*)d_in[1];
    const float* xw = (const float*)d_in[2];
    const float* yw = (const float*)d_in[3];
    float* out = (float*)d_out;

    hipLaunchKernelGGL(sinkhorn_kernel, dim3(NBLKS), dim3(BTHR), 0, stream,
                       x, y, xw, yw, out);
}